// Round 1
// baseline (584.697 us; speedup 1.0000x reference)
//
#include <hip/hip_runtime.h>
#include <math.h>

#define LEVELS 80

// One thread computes sin/cos for 2 consecutive levels of one position and
// writes a float4 (16B/lane, fully coalesced).
__global__ __launch_bounds__(256) void pe_kernel(float* __restrict__ out, int n_pos) {
    __shared__ float s_scale[LEVELS];
    int t = threadIdx.x;
    if (t < LEVELS) {
        // 1.25^t in double-double (exact to ~106 bits), then round to f32.
        // Matches numpy's correctly-rounded f32 powf bit-for-bit.
        double hi = 1.0, lo = 0.0;
        for (int j = 0; j < t; ++j) {
            double p = hi * 1.25;
            double e = fma(hi, 1.25, -p);   // exact product error
            lo = fma(lo, 1.25, e);
            double s = p + lo;              // renormalize
            lo = lo - (s - p);
            hi = s;
        }
        float pf32 = (float)hi;
        // np.float32(np.pi) = 0x40490FDB; multiply in f32 like numpy does.
        s_scale[t] = pf32 * 3.14159274101257324f;
    }
    __syncthreads();

    const int total = n_pos * (LEVELS / 2);       // 20,000,000 < 2^31
    int idx = blockIdx.x * blockDim.x + threadIdx.x;
    if (idx >= total) return;

    unsigned int u = (unsigned int)idx;
    unsigned int p  = u / 40u;                    // position
    unsigned int i2 = u - p * 40u;                // level pair index

    float pf = (float)p;                          // exact: p < 2^24
    float v0 = pf * s_scale[2 * i2];              // f32 mul, same rounding as ref
    float v1 = pf * s_scale[2 * i2 + 1];

    float s0, c0, s1, c1;
    sincosf(v0, &s0, &c0);                        // OCML: full-range accurate reduction
    sincosf(v1, &s1, &c1);

    float4 r;
    r.x = s0; r.y = c0; r.z = s1; r.w = c1;
    reinterpret_cast<float4*>(out)[idx] = r;
}

extern "C" void kernel_launch(void* const* d_in, const int* in_sizes, int n_in,
                              void* d_out, int out_size, void* d_ws, size_t ws_size,
                              hipStream_t stream) {
    (void)d_in; (void)n_in; (void)d_ws; (void)ws_size;
    int n_pos = in_sizes[0];                      // 500000; pos values are unused by the reference
    int total = n_pos * (LEVELS / 2);
    int threads = 256;
    int blocks = (total + threads - 1) / threads;
    pe_kernel<<<blocks, threads, 0, stream>>>((float*)d_out, n_pos);
}

// Round 2
// 523.589 us; speedup vs baseline: 1.1167x; 1.1167x over previous
//
#include <hip/hip_runtime.h>
#include <math.h>
#include <stdint.h>

#define LEVELS 80

// Bits of 1/(2*pi) = 0.28BE60DB 9391054A 7F09D5F4 7D4D3770 36D8A566 4F10E410 ...
// (derived from the classic fdlibm 2/pi chunk table, shifted right 2 bits).
// Word j holds fractional bits [32j+1 .. 32j+32].
__device__ const uint32_t INV2PI_BITS[9] = {
    0x28BE60DBu, 0x9391054Au, 0x7F09D5F4u, 0x7D4D3770u, 0x36D8A566u,
    0x4F10E410u, 0x7F9458EAu, 0xF7AEF158u, 0x6DC91B8Eu
};

__device__ __forceinline__ uint32_t inv2pi_word(int q) {
    return (q < 0 || q > 8) ? 0u : INV2PI_BITS[q];
}

// Exact-argument sincos for v >= 0 (f32). Uses per-exponent 96-bit fixed-point
// table of frac(2^E/(2pi)): frac(v/2pi) = m * T[E] mod 1 with ~2^-62 turn error.
__device__ __forceinline__ void sincos_exact(
        float v, const uint32_t* __restrict__ t0, const uint32_t* __restrict__ t1,
        const uint32_t* __restrict__ t2, float& s_out, float& c_out) {
    uint32_t bits = __float_as_uint(v);
    int E = (int)((bits >> 23) & 0xFFu) - 150;      // v = m * 2^E, m in [2^23, 2^24)
    uint32_t m = (bits & 0x7FFFFFu) | 0x800000u;
    int idx = E + 22;                                // in [0,45] for all v >= pi
    idx = idx < 0 ? 0 : (idx > 47 ? 47 : idx);       // p==0 (v==0) clamped, fixed below
    // frac(v/2pi) in 2^-64 turn units
    uint64_t f = ((uint64_t)(m * t0[idx]) << 32)
               + (uint64_t)m * (uint64_t)t1[idx]
               + (((uint64_t)m * (uint64_t)t2[idx]) >> 32);
    // nearest quadrant (u64 wraparound handles frac ~ 1.0 correctly)
    uint32_t q = (uint32_t)((f + 0x2000000000000000ULL) >> 62);
    // residual = f - q*2^62, arithmetic >>32 == high word; |rhi| <= 2^29
    int32_t rhi = (int32_t)((uint32_t)(f >> 32) - (q << 30));
    float th = (float)rhi * 1.46291807926715968e-9f; // * 2pi/2^32 -> [-pi/4, pi/4]
    float z = th * th;
    float s = th * fmaf(z, fmaf(z, fmaf(z, -1.98412698e-4f, 8.33333333e-3f),
                                 -1.66666667e-1f), 1.0f);
    float c = fmaf(z, fmaf(z, fmaf(z, fmaf(z, 2.48015873e-5f, -1.38888889e-3f),
                                   4.16666667e-2f), -0.5f), 1.0f);
    float ss = (q & 1u) ? c : s;
    float cc = (q & 1u) ? s : c;
    ss = (q & 2u) ? -ss : ss;
    cc = ((q + 1u) & 2u) ? -cc : cc;
    s_out = (bits == 0u) ? 0.0f : ss;
    c_out = (bits == 0u) ? 1.0f : cc;
}

__global__ __launch_bounds__(256) void pe_kernel(float* __restrict__ out, int n_pos) {
    __shared__ float s_scale[LEVELS];
    __shared__ uint32_t s_t0[48], s_t1[48], s_t2[48];
    int t = threadIdx.x;
    if (t < LEVELS) {
        // 1.25^t in double-double (exact), rounded to f32 — matches numpy's
        // correctly-rounded f32 pow bit-for-bit; then f32 multiply by f32(pi).
        double hi = 1.0, lo = 0.0;
        for (int j = 0; j < t; ++j) {
            double p = hi * 1.25;
            double e = fma(hi, 1.25, -p);
            lo = fma(lo, 1.25, e);
            double s2 = p + lo;
            lo = lo - (s2 - p);
            hi = s2;
        }
        s_scale[t] = (float)hi * 3.14159274101257324f;
    }
    if (t < 48) {
        // Build frac(2^E/(2pi)) to 96 bits for E = t-22: result bit k is
        // 1/(2pi) bit (k+E); extract three 32-bit words via 64-bit windows.
        int E = t - 22;
        uint32_t w[3];
        #pragma unroll
        for (int i = 0; i < 3; ++i) {
            int bpos = 32 * i + E;
            int q = bpos >> 5;            // arithmetic shift = floor div
            int r = bpos & 31;
            uint64_t win = ((uint64_t)inv2pi_word(q) << 32) | (uint64_t)inv2pi_word(q + 1);
            w[i] = (uint32_t)(win >> (32 - r));
        }
        s_t0[t] = w[0]; s_t1[t] = w[1]; s_t2[t] = w[2];
    }
    __syncthreads();

    const int total = n_pos * (LEVELS / 2);   // 20,000,000
    int idx = blockIdx.x * blockDim.x + t;
    if (idx >= total) return;

    uint32_t u = (uint32_t)idx;
    uint32_t p = u / 40u;                     // position
    uint32_t i2 = u - p * 40u;                // level pair
    float pf = (float)p;                      // exact, p < 2^24
    float v0 = pf * s_scale[2 * i2];          // same f32 rounding as reference
    float v1 = pf * s_scale[2 * i2 + 1];

    float s0, c0, s1, c1;
    sincos_exact(v0, s_t0, s_t1, s_t2, s0, c0);
    sincos_exact(v1, s_t0, s_t1, s_t2, s1, c1);

    float4 r;
    r.x = s0; r.y = c0; r.z = s1; r.w = c1;
    reinterpret_cast<float4*>(out)[idx] = r;
}

extern "C" void kernel_launch(void* const* d_in, const int* in_sizes, int n_in,
                              void* d_out, int out_size, void* d_ws, size_t ws_size,
                              hipStream_t stream) {
    (void)d_in; (void)n_in; (void)d_ws; (void)ws_size; (void)out_size;
    int n_pos = in_sizes[0];                  // 500000; pos values unused by reference
    int total = n_pos * (LEVELS / 2);
    int threads = 256;
    int blocks = (total + threads - 1) / threads;
    pe_kernel<<<blocks, threads, 0, stream>>>((float*)d_out, n_pos);
}